// Round 2
// baseline (1460.277 us; speedup 1.0000x reference)
//
#include <hip/hip_runtime.h>
#include <stdint.h>
#include <math.h>

#define B_  4
#define S_  2048
#define H_  2048
#define NH_ 16
#define HD_ 128
#define M_  (B_*S_)     // 8192 rows
#define N3_ (3*H_)      // 6144

typedef __attribute__((ext_vector_type(8))) short short8;
typedef __attribute__((ext_vector_type(4))) float floatx4;

__device__ __forceinline__ unsigned short f2bf(float f) {
  unsigned u = __float_as_uint(f);
  u += 0x7FFF + ((u >> 16) & 1);          // round-to-nearest-even
  return (unsigned short)(u >> 16);
}

// ---------------------------------------------------------------- LayerNorm
__global__ __launch_bounds__(256) void ln_kernel(
    const float* __restrict__ x, const float* __restrict__ w,
    const float* __restrict__ b, unsigned short* __restrict__ xn) {
  int row = blockIdx.x;
  int t = threadIdx.x;
  const float* xr = x + (size_t)row * H_;
  float4 v0 = *(const float4*)(xr + t * 4);
  float4 v1 = *(const float4*)(xr + 1024 + t * 4);
  float s  = v0.x + v0.y + v0.z + v0.w + v1.x + v1.y + v1.z + v1.w;
  float sq = v0.x*v0.x + v0.y*v0.y + v0.z*v0.z + v0.w*v0.w
           + v1.x*v1.x + v1.y*v1.y + v1.z*v1.z + v1.w*v1.w;
  #pragma unroll
  for (int m = 32; m; m >>= 1) { s += __shfl_xor(s, m); sq += __shfl_xor(sq, m); }
  __shared__ float red[8];
  int wv = t >> 6;
  if ((t & 63) == 0) { red[wv * 2] = s; red[wv * 2 + 1] = sq; }
  __syncthreads();
  s  = red[0] + red[2] + red[4] + red[6];
  sq = red[1] + red[3] + red[5] + red[7];
  float mu  = s * (1.0f / H_);
  float var = sq * (1.0f / H_) - mu * mu;
  float rs  = rsqrtf(var + 1e-5f);

  float4 w0 = *(const float4*)(w + t * 4);
  float4 b0 = *(const float4*)(b + t * 4);
  float4 w1 = *(const float4*)(w + 1024 + t * 4);
  float4 b1 = *(const float4*)(b + 1024 + t * 4);
  ushort4 o0, o1;
  o0.x = f2bf((v0.x - mu) * rs * w0.x + b0.x);
  o0.y = f2bf((v0.y - mu) * rs * w0.y + b0.y);
  o0.z = f2bf((v0.z - mu) * rs * w0.z + b0.z);
  o0.w = f2bf((v0.w - mu) * rs * w0.w + b0.w);
  o1.x = f2bf((v1.x - mu) * rs * w1.x + b1.x);
  o1.y = f2bf((v1.y - mu) * rs * w1.y + b1.y);
  o1.z = f2bf((v1.z - mu) * rs * w1.z + b1.z);
  o1.w = f2bf((v1.w - mu) * rs * w1.w + b1.w);
  unsigned short* orow = xn + (size_t)row * H_;
  *(ushort4*)(orow + t * 4) = o0;
  *(ushort4*)(orow + 1024 + t * 4) = o1;
}

// ------------------------------------------- fp32 [R][C] -> bf16 [C][R] (Wt)
__global__ __launch_bounds__(256) void transpose_f2b(
    const float* __restrict__ in, unsigned short* __restrict__ out,
    int R, int C) {
  __shared__ float tile[32][33];
  int tx = threadIdx.x & 31, ty = threadIdx.x >> 5;   // ty 0..7
  int c0 = blockIdx.x * 32, r0 = blockIdx.y * 32;
  #pragma unroll
  for (int i = 0; i < 32; i += 8)
    tile[ty + i][tx] = in[(size_t)(r0 + ty + i) * C + c0 + tx];
  __syncthreads();
  #pragma unroll
  for (int i = 0; i < 32; i += 8)
    out[(size_t)(c0 + ty + i) * R + r0 + tx] = f2bf(tile[tx][ty + i]);
}

// ---------------------------------------------------------------- QKV GEMM
__global__ __launch_bounds__(256) void qkv_gemm(
    const unsigned short* __restrict__ A, const unsigned short* __restrict__ Bt,
    const float* __restrict__ bias,
    unsigned short* __restrict__ qw, unsigned short* __restrict__ kw,
    unsigned short* __restrict__ vtw) {
  __shared__ unsigned short As[128 * 72];
  __shared__ unsigned short Bs[128 * 72];
  int n0 = blockIdx.x * 128, m0 = blockIdx.y * 128;
  int t = threadIdx.x, lane = t & 63, wv = t >> 6;
  int l15 = lane & 15, quad = lane >> 4;
  int wm = wv >> 1, wn = wv & 1;
  floatx4 acc[4][4];
  #pragma unroll
  for (int i = 0; i < 4; i++)
    #pragma unroll
    for (int j = 0; j < 4; j++) acc[i][j] = (floatx4){0.f, 0.f, 0.f, 0.f};

  int sr = t >> 3, sc = (t & 7) * 8;
  for (int k0 = 0; k0 < H_; k0 += 64) {
    __syncthreads();
    #pragma unroll
    for (int c = 0; c < 4; c++) {
      int row = c * 32 + sr;
      *(short8*)(As + row * 72 + sc) =
          *(const short8*)(A + (size_t)(m0 + row) * H_ + k0 + sc);
      *(short8*)(Bs + row * 72 + sc) =
          *(const short8*)(Bt + (size_t)(n0 + row) * H_ + k0 + sc);
    }
    __syncthreads();
    #pragma unroll
    for (int ks = 0; ks < 2; ks++) {
      short8 af[4], bf[4];
      #pragma unroll
      for (int i = 0; i < 4; i++)
        af[i] = *(const short8*)(As + (wm * 64 + i * 16 + l15) * 72 + ks * 32 + quad * 8);
      #pragma unroll
      for (int j = 0; j < 4; j++)
        bf[j] = *(const short8*)(Bs + (wn * 64 + j * 16 + l15) * 72 + ks * 32 + quad * 8);
      #pragma unroll
      for (int i = 0; i < 4; i++)
        #pragma unroll
        for (int j = 0; j < 4; j++)
          acc[i][j] = __builtin_amdgcn_mfma_f32_16x16x32_bf16(af[i], bf[j], acc[i][j], 0, 0, 0);
    }
  }
  int sec = n0 >> 11;              // 0:Q 1:K 2:V (block never straddles)
  int h = (n0 >> 7) & 15;          // head (block never straddles)
  #pragma unroll
  for (int j = 0; j < 4; j++) {
    int d = wn * 64 + j * 16 + l15;
    float bval = bias[n0 + d];
    #pragma unroll
    for (int i = 0; i < 4; i++) {
      #pragma unroll
      for (int reg = 0; reg < 4; reg++) {
        int m = m0 + wm * 64 + i * 16 + quad * 4 + reg;
        unsigned short bv = f2bf(acc[i][j][reg] + bval);
        int bb = m >> 11, s = m & 2047;
        int bh = bb * NH_ + h;
        if (sec == 0)      qw[((size_t)bh * S_ + s) * HD_ + d] = bv;
        else if (sec == 1) kw[((size_t)bh * S_ + s) * HD_ + d] = bv;
        else               vtw[((size_t)bh * HD_ + d) * S_ + s] = bv;
      }
    }
  }
}

// ----------------------------------------------------------- Proj GEMM + res
__global__ __launch_bounds__(256) void proj_gemm(
    const unsigned short* __restrict__ A, const unsigned short* __restrict__ Bt,
    const float* __restrict__ bias, const float* __restrict__ resid,
    float* __restrict__ out) {
  __shared__ unsigned short As[128 * 72];
  __shared__ unsigned short Bs[128 * 72];
  int n0 = blockIdx.x * 128, m0 = blockIdx.y * 128;
  int t = threadIdx.x, lane = t & 63, wv = t >> 6;
  int l15 = lane & 15, quad = lane >> 4;
  int wm = wv >> 1, wn = wv & 1;
  floatx4 acc[4][4];
  #pragma unroll
  for (int i = 0; i < 4; i++)
    #pragma unroll
    for (int j = 0; j < 4; j++) acc[i][j] = (floatx4){0.f, 0.f, 0.f, 0.f};

  int sr = t >> 3, sc = (t & 7) * 8;
  for (int k0 = 0; k0 < H_; k0 += 64) {
    __syncthreads();
    #pragma unroll
    for (int c = 0; c < 4; c++) {
      int row = c * 32 + sr;
      *(short8*)(As + row * 72 + sc) =
          *(const short8*)(A + (size_t)(m0 + row) * H_ + k0 + sc);
      *(short8*)(Bs + row * 72 + sc) =
          *(const short8*)(Bt + (size_t)(n0 + row) * H_ + k0 + sc);
    }
    __syncthreads();
    #pragma unroll
    for (int ks = 0; ks < 2; ks++) {
      short8 af[4], bf[4];
      #pragma unroll
      for (int i = 0; i < 4; i++)
        af[i] = *(const short8*)(As + (wm * 64 + i * 16 + l15) * 72 + ks * 32 + quad * 8);
      #pragma unroll
      for (int j = 0; j < 4; j++)
        bf[j] = *(const short8*)(Bs + (wn * 64 + j * 16 + l15) * 72 + ks * 32 + quad * 8);
      #pragma unroll
      for (int i = 0; i < 4; i++)
        #pragma unroll
        for (int j = 0; j < 4; j++)
          acc[i][j] = __builtin_amdgcn_mfma_f32_16x16x32_bf16(af[i], bf[j], acc[i][j], 0, 0, 0);
    }
  }
  #pragma unroll
  for (int j = 0; j < 4; j++) {
    int n = n0 + wn * 64 + j * 16 + l15;
    float bval = bias[n];
    #pragma unroll
    for (int i = 0; i < 4; i++) {
      #pragma unroll
      for (int reg = 0; reg < 4; reg++) {
        int m = m0 + wm * 64 + i * 16 + quad * 4 + reg;
        out[(size_t)m * H_ + n] = acc[i][j][reg] + bval + resid[(size_t)m * H_ + n];
      }
    }
  }
}

// ------------------------------------------------------- causal flash attn
// Barrier-free S^T formulation. q,k: [BH][S][HD] bf16; vt: [BH][HD][S] bf16.
// Each wave owns 16 q-rows (q = qr + l15, one q-row per lane, replicated x4
// quads). S^T = K.Q^T (A=K-frag from global, B=Q-frag in regs); softmax state
// per-lane; P^T staged through wave-private LDS (in-order DS pipe, no
// barrier); O^T = V^T.P^T with V^T-frags direct from global (L2-resident).
__global__ __launch_bounds__(256) void attn_kernel(
    const unsigned short* __restrict__ qw, const unsigned short* __restrict__ kw,
    const unsigned short* __restrict__ vtw, unsigned short* __restrict__ ow) {
  __shared__ unsigned short Pl[4][16 * 72];   // [wave][q(16)][key 64 + pad 8]
  int qt = blockIdx.x, bh = blockIdx.y;
  int t = threadIdx.x, lane = t & 63, wv = t >> 6;
  int l15 = lane & 15, quad = lane >> 4;
  int qb = qt * 64;
  int qr = qb + wv * 16;
  int q = qr + l15;                           // this lane's q-row

  // Q-frags (B operand): lane n=l15 -> row q; k = ks*32 + quad*8 + j
  short8 qf[4];
  const unsigned short* qbase = qw + ((size_t)bh * S_ + q) * HD_ + quad * 8;
  #pragma unroll
  for (int ks = 0; ks < 4; ks++)
    qf[ks] = *(const short8*)(qbase + ks * 32);

  float m_i = -INFINITY, l_i = 0.f;           // per-lane softmax state (q=l15)
  floatx4 o[8];
  #pragma unroll
  for (int ht = 0; ht < 8; ht++) o[ht] = (floatx4){0.f, 0.f, 0.f, 0.f};

  const float scale = 0.08838834764831845f;
  const unsigned short* kbase = kw + ((size_t)bh * S_ + l15) * HD_ + quad * 8;
  const unsigned short* vbase = vtw + ((size_t)bh * HD_ + l15) * S_ + quad * 8;
  unsigned short* plw = &Pl[wv][0];

  for (int kt = 0; kt <= qt; kt++) {
    int kb = kt * 64;
    // ---- K-frags (A operand): key = kb + jm*16 + l15, d = ks*32 + quad*8
    short8 kf[4][4];
    #pragma unroll
    for (int jm = 0; jm < 4; jm++)
      #pragma unroll
      for (int ks = 0; ks < 4; ks++)
        kf[jm][ks] = *(const short8*)(kbase + (size_t)(kb + jm * 16) * HD_ + ks * 32);

    // ---- S^T = K.Q^T
    floatx4 sv[4];
    #pragma unroll
    for (int jm = 0; jm < 4; jm++) {
      sv[jm] = (floatx4){0.f, 0.f, 0.f, 0.f};
      #pragma unroll
      for (int ks = 0; ks < 4; ks++)
        sv[jm] = __builtin_amdgcn_mfma_f32_16x16x32_bf16(kf[jm][ks], qf[ks], sv[jm], 0, 0, 0);
    }

    // ---- online softmax (lane holds 16 scores for its q-row)
    float p[4][4];
    float mx = m_i;
    #pragma unroll
    for (int jm = 0; jm < 4; jm++)
      #pragma unroll
      for (int reg = 0; reg < 4; reg++) {
        float v = sv[jm][reg] * scale;
        int key = kb + jm * 16 + quad * 4 + reg;
        if (key > q) v = -1e30f;
        p[jm][reg] = v;
        mx = fmaxf(mx, v);
      }
    mx = fmaxf(mx, __shfl_xor(mx, 16));
    mx = fmaxf(mx, __shfl_xor(mx, 32));
    float sum = 0.f;
    #pragma unroll
    for (int jm = 0; jm < 4; jm++)
      #pragma unroll
      for (int reg = 0; reg < 4; reg++) { p[jm][reg] = __expf(p[jm][reg] - mx); sum += p[jm][reg]; }
    sum += __shfl_xor(sum, 16);
    sum += __shfl_xor(sum, 32);
    float alpha = __expf(m_i - mx);
    l_i = l_i * alpha + sum;
    m_i = mx;
    #pragma unroll
    for (int ht = 0; ht < 8; ht++) o[ht] *= alpha;

    // ---- P^T -> LDS [q=l15][key], packed 4 bf16 (8B) per jm
    #pragma unroll
    for (int jm = 0; jm < 4; jm++) {
      ushort4 pk;
      pk.x = f2bf(p[jm][0]); pk.y = f2bf(p[jm][1]);
      pk.z = f2bf(p[jm][2]); pk.w = f2bf(p[jm][3]);
      *(ushort4*)(plw + l15 * 72 + jm * 16 + quad * 4) = pk;
    }

    // ---- O^T += V^T.P^T  (V^T-frags direct from global/L2)
    #pragma unroll
    for (int ks2 = 0; ks2 < 2; ks2++) {
      short8 pf = *(const short8*)(plw + l15 * 72 + ks2 * 32 + quad * 8);
      #pragma unroll
      for (int ht = 0; ht < 8; ht++) {
        short8 vf = *(const short8*)(vbase + (size_t)(ht * 16) * S_ + kb + ks2 * 32);
        o[ht] = __builtin_amdgcn_mfma_f32_16x16x32_bf16(vf, pf, o[ht], 0, 0, 0);
      }
    }
  }

  // ---- epilogue: lane holds O^T: q = l15, d = ht*16 + quad*4 + reg
  int h = bh & 15, bb = bh >> 4;
  float inv = 1.0f / l_i;
  size_t base = ((size_t)(bb * S_ + q)) * H_ + h * HD_ + quad * 4;
  #pragma unroll
  for (int ht = 0; ht < 8; ht++) {
    ushort4 ov;
    ov.x = f2bf(o[ht][0] * inv); ov.y = f2bf(o[ht][1] * inv);
    ov.z = f2bf(o[ht][2] * inv); ov.w = f2bf(o[ht][3] * inv);
    *(ushort4*)(ow + base + ht * 16) = ov;
  }
}

// ---------------------------------------------------------------- launcher
extern "C" void kernel_launch(void* const* d_in, const int* in_sizes, int n_in,
                              void* d_out, int out_size, void* d_ws, size_t ws_size,
                              hipStream_t stream) {
  (void)in_sizes; (void)n_in; (void)out_size; (void)ws_size;
  const float* x      = (const float*)d_in[0];
  const float* ln_w   = (const float*)d_in[1];
  const float* ln_b   = (const float*)d_in[2];
  const float* attn_w = (const float*)d_in[3];
  const float* attn_b = (const float*)d_in[4];
  const float* proj_w = (const float*)d_in[5];
  const float* proj_b = (const float*)d_in[6];
  float* out = (float*)d_out;

  char* ws = (char*)d_ws;
  size_t off = 0;
  auto alloc = [&](size_t bytes) {
    char* p = ws + off;
    off += (bytes + 255) & ~(size_t)255;
    return p;
  };
  unsigned short* xn     = (unsigned short*)alloc((size_t)M_ * H_ * 2);
  unsigned short* wqkvt  = (unsigned short*)alloc((size_t)N3_ * H_ * 2);
  unsigned short* wprojt = (unsigned short*)alloc((size_t)H_ * H_ * 2);
  unsigned short* qws    = (unsigned short*)alloc((size_t)M_ * H_ * 2);
  unsigned short* kws    = (unsigned short*)alloc((size_t)M_ * H_ * 2);
  unsigned short* vtws   = (unsigned short*)alloc((size_t)M_ * H_ * 2);
  unsigned short* attn_out = xn;   // xn dead after qkv_gemm — alias

  ln_kernel<<<M_, 256, 0, stream>>>(x, ln_w, ln_b, xn);
  transpose_f2b<<<dim3(N3_ / 32, H_ / 32), 256, 0, stream>>>(attn_w, wqkvt, H_, N3_);
  transpose_f2b<<<dim3(H_ / 32, H_ / 32), 256, 0, stream>>>(proj_w, wprojt, H_, H_);
  qkv_gemm<<<dim3(N3_ / 128, M_ / 128), 256, 0, stream>>>(xn, wqkvt, attn_b, qws, kws, vtws);
  attn_kernel<<<dim3(S_ / 64, B_ * NH_), 256, 0, stream>>>(qws, kws, vtws, attn_out);
  proj_gemm<<<dim3(H_ / 128, M_ / 128), 256, 0, stream>>>(attn_out, wprojt, proj_b, x, out);
}

// Round 3
// 736.839 us; speedup vs baseline: 1.9818x; 1.9818x over previous
//
#include <hip/hip_runtime.h>
#include <stdint.h>
#include <math.h>

#define B_  4
#define S_  2048
#define H_  2048
#define NH_ 16
#define HD_ 128
#define M_  (B_*S_)     // 8192 rows
#define N3_ (3*H_)      // 6144
#define NQT_ (S_/64)    // 32 q-tiles of 64 rows

typedef __attribute__((ext_vector_type(8))) short short8;
typedef __attribute__((ext_vector_type(4))) float floatx4;

__device__ __forceinline__ unsigned short f2bf(float f) {
  unsigned u = __float_as_uint(f);
  u += 0x7FFF + ((u >> 16) & 1);          // round-to-nearest-even
  return (unsigned short)(u >> 16);
}

// ---------------------------------------------------------------- LayerNorm
__global__ __launch_bounds__(256) void ln_kernel(
    const float* __restrict__ x, const float* __restrict__ w,
    const float* __restrict__ b, unsigned short* __restrict__ xn) {
  int row = blockIdx.x;
  int t = threadIdx.x;
  const float* xr = x + (size_t)row * H_;
  float4 v0 = *(const float4*)(xr + t * 4);
  float4 v1 = *(const float4*)(xr + 1024 + t * 4);
  float s  = v0.x + v0.y + v0.z + v0.w + v1.x + v1.y + v1.z + v1.w;
  float sq = v0.x*v0.x + v0.y*v0.y + v0.z*v0.z + v0.w*v0.w
           + v1.x*v1.x + v1.y*v1.y + v1.z*v1.z + v1.w*v1.w;
  #pragma unroll
  for (int m = 32; m; m >>= 1) { s += __shfl_xor(s, m); sq += __shfl_xor(sq, m); }
  __shared__ float red[8];
  int wv = t >> 6;
  if ((t & 63) == 0) { red[wv * 2] = s; red[wv * 2 + 1] = sq; }
  __syncthreads();
  s  = red[0] + red[2] + red[4] + red[6];
  sq = red[1] + red[3] + red[5] + red[7];
  float mu  = s * (1.0f / H_);
  float var = sq * (1.0f / H_) - mu * mu;
  float rs  = rsqrtf(var + 1e-5f);

  float4 w0 = *(const float4*)(w + t * 4);
  float4 b0 = *(const float4*)(b + t * 4);
  float4 w1 = *(const float4*)(w + 1024 + t * 4);
  float4 b1 = *(const float4*)(b + 1024 + t * 4);
  ushort4 o0, o1;
  o0.x = f2bf((v0.x - mu) * rs * w0.x + b0.x);
  o0.y = f2bf((v0.y - mu) * rs * w0.y + b0.y);
  o0.z = f2bf((v0.z - mu) * rs * w0.z + b0.z);
  o0.w = f2bf((v0.w - mu) * rs * w0.w + b0.w);
  o1.x = f2bf((v1.x - mu) * rs * w1.x + b1.x);
  o1.y = f2bf((v1.y - mu) * rs * w1.y + b1.y);
  o1.z = f2bf((v1.z - mu) * rs * w1.z + b1.z);
  o1.w = f2bf((v1.w - mu) * rs * w1.w + b1.w);
  unsigned short* orow = xn + (size_t)row * H_;
  *(ushort4*)(orow + t * 4) = o0;
  *(ushort4*)(orow + 1024 + t * 4) = o1;
}

// ------------------------------------------- fp32 [R][C] -> bf16 [C][R] (Wt)
__global__ __launch_bounds__(256) void transpose_f2b(
    const float* __restrict__ in, unsigned short* __restrict__ out,
    int R, int C) {
  __shared__ float tile[32][33];
  int tx = threadIdx.x & 31, ty = threadIdx.x >> 5;   // ty 0..7
  int c0 = blockIdx.x * 32, r0 = blockIdx.y * 32;
  #pragma unroll
  for (int i = 0; i < 32; i += 8)
    tile[ty + i][tx] = in[(size_t)(r0 + ty + i) * C + c0 + tx];
  __syncthreads();
  #pragma unroll
  for (int i = 0; i < 32; i += 8)
    out[(size_t)(c0 + ty + i) * R + r0 + tx] = f2bf(tile[tx][ty + i]);
}

// ---------------------------------------------------------------- QKV GEMM
__global__ __launch_bounds__(256) void qkv_gemm(
    const unsigned short* __restrict__ A, const unsigned short* __restrict__ Bt,
    const float* __restrict__ bias,
    unsigned short* __restrict__ qw, unsigned short* __restrict__ kw,
    unsigned short* __restrict__ vtw) {
  __shared__ unsigned short As[128 * 72];
  __shared__ unsigned short Bs[128 * 72];
  int n0 = blockIdx.x * 128, m0 = blockIdx.y * 128;
  int t = threadIdx.x, lane = t & 63, wv = t >> 6;
  int l15 = lane & 15, quad = lane >> 4;
  int wm = wv >> 1, wn = wv & 1;
  floatx4 acc[4][4];
  #pragma unroll
  for (int i = 0; i < 4; i++)
    #pragma unroll
    for (int j = 0; j < 4; j++) acc[i][j] = (floatx4){0.f, 0.f, 0.f, 0.f};

  int sr = t >> 3, sc = (t & 7) * 8;
  for (int k0 = 0; k0 < H_; k0 += 64) {
    __syncthreads();
    #pragma unroll
    for (int c = 0; c < 4; c++) {
      int row = c * 32 + sr;
      *(short8*)(As + row * 72 + sc) =
          *(const short8*)(A + (size_t)(m0 + row) * H_ + k0 + sc);
      *(short8*)(Bs + row * 72 + sc) =
          *(const short8*)(Bt + (size_t)(n0 + row) * H_ + k0 + sc);
    }
    __syncthreads();
    #pragma unroll
    for (int ks = 0; ks < 2; ks++) {
      short8 af[4], bf[4];
      #pragma unroll
      for (int i = 0; i < 4; i++)
        af[i] = *(const short8*)(As + (wm * 64 + i * 16 + l15) * 72 + ks * 32 + quad * 8);
      #pragma unroll
      for (int j = 0; j < 4; j++)
        bf[j] = *(const short8*)(Bs + (wn * 64 + j * 16 + l15) * 72 + ks * 32 + quad * 8);
      #pragma unroll
      for (int i = 0; i < 4; i++)
        #pragma unroll
        for (int j = 0; j < 4; j++)
          acc[i][j] = __builtin_amdgcn_mfma_f32_16x16x32_bf16(af[i], bf[j], acc[i][j], 0, 0, 0);
    }
  }
  int sec = n0 >> 11;              // 0:Q 1:K 2:V (block never straddles)
  int h = (n0 >> 7) & 15;          // head (block never straddles)
  #pragma unroll
  for (int j = 0; j < 4; j++) {
    int d = wn * 64 + j * 16 + l15;
    float bval = bias[n0 + d];
    #pragma unroll
    for (int i = 0; i < 4; i++) {
      #pragma unroll
      for (int reg = 0; reg < 4; reg++) {
        int m = m0 + wm * 64 + i * 16 + quad * 4 + reg;
        unsigned short bv = f2bf(acc[i][j][reg] + bval);
        int bb = m >> 11, s = m & 2047;
        int bh = bb * NH_ + h;
        if (sec == 0)      qw[((size_t)bh * S_ + s) * HD_ + d] = bv;
        else if (sec == 1) kw[((size_t)bh * S_ + s) * HD_ + d] = bv;
        else               vtw[((size_t)bh * HD_ + d) * S_ + s] = bv;
      }
    }
  }
}

// ----------------------------------------------------------- Proj GEMM + res
__global__ __launch_bounds__(256) void proj_gemm(
    const unsigned short* __restrict__ A, const unsigned short* __restrict__ Bt,
    const float* __restrict__ bias, const float* __restrict__ resid,
    float* __restrict__ out) {
  __shared__ unsigned short As[128 * 72];
  __shared__ unsigned short Bs[128 * 72];
  int n0 = blockIdx.x * 128, m0 = blockIdx.y * 128;
  int t = threadIdx.x, lane = t & 63, wv = t >> 6;
  int l15 = lane & 15, quad = lane >> 4;
  int wm = wv >> 1, wn = wv & 1;
  floatx4 acc[4][4];
  #pragma unroll
  for (int i = 0; i < 4; i++)
    #pragma unroll
    for (int j = 0; j < 4; j++) acc[i][j] = (floatx4){0.f, 0.f, 0.f, 0.f};

  int sr = t >> 3, sc = (t & 7) * 8;
  for (int k0 = 0; k0 < H_; k0 += 64) {
    __syncthreads();
    #pragma unroll
    for (int c = 0; c < 4; c++) {
      int row = c * 32 + sr;
      *(short8*)(As + row * 72 + sc) =
          *(const short8*)(A + (size_t)(m0 + row) * H_ + k0 + sc);
      *(short8*)(Bs + row * 72 + sc) =
          *(const short8*)(Bt + (size_t)(n0 + row) * H_ + k0 + sc);
    }
    __syncthreads();
    #pragma unroll
    for (int ks = 0; ks < 2; ks++) {
      short8 af[4], bf[4];
      #pragma unroll
      for (int i = 0; i < 4; i++)
        af[i] = *(const short8*)(As + (wm * 64 + i * 16 + l15) * 72 + ks * 32 + quad * 8);
      #pragma unroll
      for (int j = 0; j < 4; j++)
        bf[j] = *(const short8*)(Bs + (wn * 64 + j * 16 + l15) * 72 + ks * 32 + quad * 8);
      #pragma unroll
      for (int i = 0; i < 4; i++)
        #pragma unroll
        for (int j = 0; j < 4; j++)
          acc[i][j] = __builtin_amdgcn_mfma_f32_16x16x32_bf16(af[i], bf[j], acc[i][j], 0, 0, 0);
    }
  }
  #pragma unroll
  for (int j = 0; j < 4; j++) {
    int n = n0 + wn * 64 + j * 16 + l15;
    float bval = bias[n];
    #pragma unroll
    for (int i = 0; i < 4; i++) {
      #pragma unroll
      for (int reg = 0; reg < 4; reg++) {
        int m = m0 + wm * 64 + i * 16 + quad * 4 + reg;
        out[(size_t)m * H_ + n] = acc[i][j][reg] + bval + resid[(size_t)m * H_ + n];
      }
    }
  }
}

// ------------------------------------------------------- causal flash attn
// Block = 64 q-rows x 2 paired q-tiles (qt, 31-qt) -> uniform 33 k-tiles of
// work per block. K/Vt staged cooperatively in LDS (padded, conflict-free),
// single-reg-set software pipeline: barrier; ds_write(regs); barrier; issue
// global loads for kt+1; compute kt (prefetch drains at next barrier).
// S^T formulation: lane owns one q-row (q = qr + l15); softmax = 2 shfls;
// P^T via wave-private LDS (in-order DS pipe, no barrier).
__global__ __launch_bounds__(256) void attn_kernel(
    const unsigned short* __restrict__ qw, const unsigned short* __restrict__ kw,
    const unsigned short* __restrict__ vtw, unsigned short* __restrict__ ow) {
  __shared__ unsigned short Klds[64 * 136];   // [key 64][d 128 + pad]
  __shared__ unsigned short Vtl[128 * 72];    // [d 128][key 64 + pad]
  __shared__ unsigned short Pl[4][16 * 72];   // [wave][q 16][key 64 + pad]
  int pr = blockIdx.x, bh = blockIdx.y;
  int t = threadIdx.x, lane = t & 63, wv = t >> 6;
  int l15 = lane & 15, quad = lane >> 4;
  int h = bh & 15, bb = bh >> 4;

  const float scale = 0.08838834764831845f;
  int krr = t >> 4, kcc = (t & 15) * 8;       // K staging: 16 lanes/row
  int vdd = t >> 3, vss = (t & 7) * 8;        // Vt staging: 8 lanes/row
  unsigned short* plw = &Pl[wv][0];
  const unsigned short* kgb = kw + ((size_t)bh * S_ + krr) * HD_ + kcc;
  const unsigned short* vgb = vtw + ((size_t)bh * HD_ + vdd) * S_ + vss;

  short8 kreg[4], vreg[4];
  auto load_stage = [&](int kb) {
    #pragma unroll
    for (int c = 0; c < 4; c++) {
      kreg[c] = *(const short8*)(kgb + (size_t)(kb + c * 16) * HD_);
      vreg[c] = *(const short8*)(vgb + (size_t)(c * 32) * S_ + kb);
    }
  };

  #pragma unroll 1
  for (int half = 0; half < 2; half++) {
    int qt = half ? (NQT_ - 1 - pr) : pr;
    int qr = qt * 64 + wv * 16;
    int q = qr + l15;                         // this lane's q-row

    // Q-frags (B operand): lane n=l15 -> row q; k = ks*32 + quad*8 + j
    short8 qf[4];
    {
      const unsigned short* qbase = qw + ((size_t)bh * S_ + q) * HD_ + quad * 8;
      #pragma unroll
      for (int ks = 0; ks < 4; ks++)
        qf[ks] = *(const short8*)(qbase + ks * 32);
    }

    float m_i = -INFINITY, l_i = 0.f;
    floatx4 o[8];
    #pragma unroll
    for (int ht = 0; ht < 8; ht++) o[ht] = (floatx4){0.f, 0.f, 0.f, 0.f};

    load_stage(0);                            // prime the pipeline
    #pragma unroll 1
    for (int kt = 0; kt <= qt; kt++) {
      int kb = kt * 64;
      __syncthreads();                        // prev tile's LDS reads done; prefetch drained
      #pragma unroll
      for (int c = 0; c < 4; c++) {
        *(short8*)(Klds + (c * 16 + krr) * 136 + kcc) = kreg[c];
        *(short8*)(Vtl + (c * 32 + vdd) * 72 + vss) = vreg[c];
      }
      __syncthreads();                        // tile visible to all waves
      if (kt < qt) load_stage(kb + 64);       // async prefetch overlaps compute

      // ---- S^T = K.Q^T  (A = K-frag from LDS)
      floatx4 sv[4];
      #pragma unroll
      for (int jm = 0; jm < 4; jm++) {
        sv[jm] = (floatx4){0.f, 0.f, 0.f, 0.f};
        #pragma unroll
        for (int ks = 0; ks < 4; ks++) {
          short8 kf = *(const short8*)(Klds + (jm * 16 + l15) * 136 + ks * 32 + quad * 8);
          sv[jm] = __builtin_amdgcn_mfma_f32_16x16x32_bf16(kf, qf[ks], sv[jm], 0, 0, 0);
        }
      }

      // ---- online softmax (lane holds 16 scores for its q-row)
      float p[4][4];
      float mx = m_i;
      #pragma unroll
      for (int jm = 0; jm < 4; jm++)
        #pragma unroll
        for (int reg = 0; reg < 4; reg++) {
          float v = sv[jm][reg] * scale;
          int key = kb + jm * 16 + quad * 4 + reg;
          if (key > q) v = -1e30f;
          p[jm][reg] = v;
          mx = fmaxf(mx, v);
        }
      mx = fmaxf(mx, __shfl_xor(mx, 16));
      mx = fmaxf(mx, __shfl_xor(mx, 32));
      float sum = 0.f;
      #pragma unroll
      for (int jm = 0; jm < 4; jm++)
        #pragma unroll
        for (int reg = 0; reg < 4; reg++) { p[jm][reg] = __expf(p[jm][reg] - mx); sum += p[jm][reg]; }
      sum += __shfl_xor(sum, 16);
      sum += __shfl_xor(sum, 32);
      float alpha = __expf(m_i - mx);
      l_i = l_i * alpha + sum;
      m_i = mx;
      #pragma unroll
      for (int ht = 0; ht < 8; ht++) o[ht] *= alpha;

      // ---- P^T -> wave-private LDS [q=l15][key], 8B packed
      #pragma unroll
      for (int jm = 0; jm < 4; jm++) {
        ushort4 pk;
        pk.x = f2bf(p[jm][0]); pk.y = f2bf(p[jm][1]);
        pk.z = f2bf(p[jm][2]); pk.w = f2bf(p[jm][3]);
        *(ushort4*)(plw + l15 * 72 + jm * 16 + quad * 4) = pk;
      }

      // ---- O^T += V^T.P^T  (A = Vt-frag from LDS)
      #pragma unroll
      for (int ks2 = 0; ks2 < 2; ks2++) {
        short8 pf = *(const short8*)(plw + l15 * 72 + ks2 * 32 + quad * 8);
        #pragma unroll
        for (int ht = 0; ht < 8; ht++) {
          short8 vf = *(const short8*)(Vtl + (ht * 16 + l15) * 72 + ks2 * 32 + quad * 8);
          o[ht] = __builtin_amdgcn_mfma_f32_16x16x32_bf16(vf, pf, o[ht], 0, 0, 0);
        }
      }
    }

    // ---- epilogue: lane holds O^T: q = l15-row, d = ht*16 + quad*4 + reg
    float inv = 1.0f / l_i;
    size_t base = ((size_t)(bb * S_ + q)) * H_ + h * HD_ + quad * 4;
    #pragma unroll
    for (int ht = 0; ht < 8; ht++) {
      ushort4 ov;
      ov.x = f2bf(o[ht][0] * inv); ov.y = f2bf(o[ht][1] * inv);
      ov.z = f2bf(o[ht][2] * inv); ov.w = f2bf(o[ht][3] * inv);
      *(ushort4*)(ow + base + ht * 16) = ov;
    }
  }
}

// ---------------------------------------------------------------- launcher
extern "C" void kernel_launch(void* const* d_in, const int* in_sizes, int n_in,
                              void* d_out, int out_size, void* d_ws, size_t ws_size,
                              hipStream_t stream) {
  (void)in_sizes; (void)n_in; (void)out_size; (void)ws_size;
  const float* x      = (const float*)d_in[0];
  const float* ln_w   = (const float*)d_in[1];
  const float* ln_b   = (const float*)d_in[2];
  const float* attn_w = (const float*)d_in[3];
  const float* attn_b = (const float*)d_in[4];
  const float* proj_w = (const float*)d_in[5];
  const float* proj_b = (const float*)d_in[6];
  float* out = (float*)d_out;

  char* ws = (char*)d_ws;
  size_t off = 0;
  auto alloc = [&](size_t bytes) {
    char* p = ws + off;
    off += (bytes + 255) & ~(size_t)255;
    return p;
  };
  unsigned short* xn     = (unsigned short*)alloc((size_t)M_ * H_ * 2);
  unsigned short* wqkvt  = (unsigned short*)alloc((size_t)N3_ * H_ * 2);
  unsigned short* wprojt = (unsigned short*)alloc((size_t)H_ * H_ * 2);
  unsigned short* qws    = (unsigned short*)alloc((size_t)M_ * H_ * 2);
  unsigned short* kws    = (unsigned short*)alloc((size_t)M_ * H_ * 2);
  unsigned short* vtws   = (unsigned short*)alloc((size_t)M_ * H_ * 2);
  unsigned short* attn_out = xn;   // xn dead after qkv_gemm — alias

  ln_kernel<<<M_, 256, 0, stream>>>(x, ln_w, ln_b, xn);
  transpose_f2b<<<dim3(N3_ / 32, H_ / 32), 256, 0, stream>>>(attn_w, wqkvt, H_, N3_);
  transpose_f2b<<<dim3(H_ / 32, H_ / 32), 256, 0, stream>>>(proj_w, wprojt, H_, H_);
  qkv_gemm<<<dim3(N3_ / 128, M_ / 128), 256, 0, stream>>>(xn, wqkvt, attn_b, qws, kws, vtws);
  attn_kernel<<<dim3(NQT_ / 2, B_ * NH_), 256, 0, stream>>>(qws, kws, vtws, attn_out);
  proj_gemm<<<dim3(H_ / 128, M_ / 128), 256, 0, stream>>>(attn_out, wprojt, proj_b, x, out);
}

// Round 4
// 727.002 us; speedup vs baseline: 2.0086x; 1.0135x over previous
//
#include <hip/hip_runtime.h>
#include <stdint.h>
#include <math.h>

#define B_  4
#define S_  2048
#define H_  2048
#define NH_ 16
#define HD_ 128
#define M_  (B_*S_)     // 8192 rows
#define N3_ (3*H_)      // 6144
#define NQT_ (S_/64)    // 32 q-tiles of 64 rows

typedef __attribute__((ext_vector_type(8))) short short8;
typedef __attribute__((ext_vector_type(4))) float floatx4;
typedef unsigned int u32;

__device__ __forceinline__ unsigned short f2bf(float f) {
  unsigned u = __float_as_uint(f);
  u += 0x7FFF + ((u >> 16) & 1);          // round-to-nearest-even
  return (unsigned short)(u >> 16);
}

// async 16B global -> LDS (global_load_lds_dwordx4). LDS dest must be
// wave-uniform base + lane*16 (no per-lane scatter / padding!).
__device__ __forceinline__ void gl2lds16(const void* g, void* l) {
  __builtin_amdgcn_global_load_lds(
      (const __attribute__((address_space(1))) u32*)g,
      (__attribute__((address_space(3))) u32*)l, 16, 0, 0);
}

// ---------------------------------------------------------------- LayerNorm
__global__ __launch_bounds__(256) void ln_kernel(
    const float* __restrict__ x, const float* __restrict__ w,
    const float* __restrict__ b, unsigned short* __restrict__ xn) {
  int row = blockIdx.x;
  int t = threadIdx.x;
  const float* xr = x + (size_t)row * H_;
  float4 v0 = *(const float4*)(xr + t * 4);
  float4 v1 = *(const float4*)(xr + 1024 + t * 4);
  float s  = v0.x + v0.y + v0.z + v0.w + v1.x + v1.y + v1.z + v1.w;
  float sq = v0.x*v0.x + v0.y*v0.y + v0.z*v0.z + v0.w*v0.w
           + v1.x*v1.x + v1.y*v1.y + v1.z*v1.z + v1.w*v1.w;
  #pragma unroll
  for (int m = 32; m; m >>= 1) { s += __shfl_xor(s, m); sq += __shfl_xor(sq, m); }
  __shared__ float red[8];
  int wv = t >> 6;
  if ((t & 63) == 0) { red[wv * 2] = s; red[wv * 2 + 1] = sq; }
  __syncthreads();
  s  = red[0] + red[2] + red[4] + red[6];
  sq = red[1] + red[3] + red[5] + red[7];
  float mu  = s * (1.0f / H_);
  float var = sq * (1.0f / H_) - mu * mu;
  float rs  = rsqrtf(var + 1e-5f);

  float4 w0 = *(const float4*)(w + t * 4);
  float4 b0 = *(const float4*)(b + t * 4);
  float4 w1 = *(const float4*)(w + 1024 + t * 4);
  float4 b1 = *(const float4*)(b + 1024 + t * 4);
  ushort4 o0, o1;
  o0.x = f2bf((v0.x - mu) * rs * w0.x + b0.x);
  o0.y = f2bf((v0.y - mu) * rs * w0.y + b0.y);
  o0.z = f2bf((v0.z - mu) * rs * w0.z + b0.z);
  o0.w = f2bf((v0.w - mu) * rs * w0.w + b0.w);
  o1.x = f2bf((v1.x - mu) * rs * w1.x + b1.x);
  o1.y = f2bf((v1.y - mu) * rs * w1.y + b1.y);
  o1.z = f2bf((v1.z - mu) * rs * w1.z + b1.z);
  o1.w = f2bf((v1.w - mu) * rs * w1.w + b1.w);
  unsigned short* orow = xn + (size_t)row * H_;
  *(ushort4*)(orow + t * 4) = o0;
  *(ushort4*)(orow + 1024 + t * 4) = o1;
}

// ------------------------------------------- fp32 [R][C] -> bf16 [C][R] (Wt)
__global__ __launch_bounds__(256) void transpose_f2b(
    const float* __restrict__ in, unsigned short* __restrict__ out,
    int R, int C) {
  __shared__ float tile[32][33];
  int tx = threadIdx.x & 31, ty = threadIdx.x >> 5;   // ty 0..7
  int c0 = blockIdx.x * 32, r0 = blockIdx.y * 32;
  #pragma unroll
  for (int i = 0; i < 32; i += 8)
    tile[ty + i][tx] = in[(size_t)(r0 + ty + i) * C + c0 + tx];
  __syncthreads();
  #pragma unroll
  for (int i = 0; i < 32; i += 8)
    out[(size_t)(c0 + ty + i) * R + r0 + tx] = f2bf(tile[tx][ty + i]);
}

// ---------------------------------------------------------------- QKV GEMM
// m97 structure: async global_load_lds width=16, unpadded 128x64 LDS tiles.
__global__ __launch_bounds__(256) void qkv_gemm(
    const unsigned short* __restrict__ A, const unsigned short* __restrict__ Bt,
    const float* __restrict__ bias,
    unsigned short* __restrict__ qw, unsigned short* __restrict__ kw,
    unsigned short* __restrict__ vtw) {
  __shared__ unsigned short As[128 * 64];
  __shared__ unsigned short Bs[128 * 64];
  int n0 = blockIdx.x * 128, m0 = blockIdx.y * 128;
  int t = threadIdx.x, lane = t & 63, wv = t >> 6;
  int l15 = lane & 15, quad = lane >> 4;
  int wm = wv >> 1, wn = wv & 1;
  floatx4 acc[4][4];
  #pragma unroll
  for (int i = 0; i < 4; i++)
    #pragma unroll
    for (int j = 0; j < 4; j++) acc[i][j] = (floatx4){0.f, 0.f, 0.f, 0.f};

  // staging: thread t -> row t>>3, col (t&7)*8; LDS offset = t*16B (lane-linear)
  const unsigned short* ag = A + (size_t)(m0 + (t >> 3)) * H_ + (t & 7) * 8;
  const unsigned short* bg = Bt + (size_t)(n0 + (t >> 3)) * H_ + (t & 7) * 8;
  unsigned short* asl = As + t * 8;
  unsigned short* bsl = Bs + t * 8;

  for (int k0 = 0; k0 < H_; k0 += 64) {
    __syncthreads();
    #pragma unroll
    for (int c = 0; c < 4; c++) {
      gl2lds16(ag + (size_t)(c * 32) * H_ + k0, asl + c * 2048);
      gl2lds16(bg + (size_t)(c * 32) * H_ + k0, bsl + c * 2048);
    }
    __syncthreads();
    #pragma unroll
    for (int ks = 0; ks < 2; ks++) {
      short8 af[4], bf[4];
      #pragma unroll
      for (int i = 0; i < 4; i++)
        af[i] = *(const short8*)(As + (wm * 64 + i * 16 + l15) * 64 + ks * 32 + quad * 8);
      #pragma unroll
      for (int j = 0; j < 4; j++)
        bf[j] = *(const short8*)(Bs + (wn * 64 + j * 16 + l15) * 64 + ks * 32 + quad * 8);
      #pragma unroll
      for (int i = 0; i < 4; i++)
        #pragma unroll
        for (int j = 0; j < 4; j++)
          acc[i][j] = __builtin_amdgcn_mfma_f32_16x16x32_bf16(af[i], bf[j], acc[i][j], 0, 0, 0);
    }
  }
  int sec = n0 >> 11;              // 0:Q 1:K 2:V (block never straddles)
  int h = (n0 >> 7) & 15;          // head (block never straddles)
  #pragma unroll
  for (int j = 0; j < 4; j++) {
    int d = wn * 64 + j * 16 + l15;
    float bval = bias[n0 + d];
    #pragma unroll
    for (int i = 0; i < 4; i++) {
      int m = m0 + wm * 64 + i * 16 + quad * 4;   // 4 consecutive rows
      int bb = m >> 11, s = m & 2047;
      int bh = bb * NH_ + h;
      if (sec == 2) {
        ushort4 pv;
        pv.x = f2bf(acc[i][j][0] + bval); pv.y = f2bf(acc[i][j][1] + bval);
        pv.z = f2bf(acc[i][j][2] + bval); pv.w = f2bf(acc[i][j][3] + bval);
        *(ushort4*)(vtw + ((size_t)bh * HD_ + d) * S_ + s) = pv;
      } else {
        unsigned short* dst = (sec == 0 ? qw : kw) + ((size_t)bh * S_ + s) * HD_ + d;
        #pragma unroll
        for (int reg = 0; reg < 4; reg++)
          dst[(size_t)reg * HD_] = f2bf(acc[i][j][reg] + bval);
      }
    }
  }
}

// ----------------------------------------------------------- Proj GEMM + res
__global__ __launch_bounds__(256) void proj_gemm(
    const unsigned short* __restrict__ A, const unsigned short* __restrict__ Bt,
    const float* __restrict__ bias, const float* __restrict__ resid,
    float* __restrict__ out) {
  __shared__ unsigned short As[128 * 64];
  __shared__ unsigned short Bs[128 * 64];
  int n0 = blockIdx.x * 128, m0 = blockIdx.y * 128;
  int t = threadIdx.x, lane = t & 63, wv = t >> 6;
  int l15 = lane & 15, quad = lane >> 4;
  int wm = wv >> 1, wn = wv & 1;
  floatx4 acc[4][4];
  #pragma unroll
  for (int i = 0; i < 4; i++)
    #pragma unroll
    for (int j = 0; j < 4; j++) acc[i][j] = (floatx4){0.f, 0.f, 0.f, 0.f};

  const unsigned short* ag = A + (size_t)(m0 + (t >> 3)) * H_ + (t & 7) * 8;
  const unsigned short* bg = Bt + (size_t)(n0 + (t >> 3)) * H_ + (t & 7) * 8;
  unsigned short* asl = As + t * 8;
  unsigned short* bsl = Bs + t * 8;

  for (int k0 = 0; k0 < H_; k0 += 64) {
    __syncthreads();
    #pragma unroll
    for (int c = 0; c < 4; c++) {
      gl2lds16(ag + (size_t)(c * 32) * H_ + k0, asl + c * 2048);
      gl2lds16(bg + (size_t)(c * 32) * H_ + k0, bsl + c * 2048);
    }
    __syncthreads();
    #pragma unroll
    for (int ks = 0; ks < 2; ks++) {
      short8 af[4], bf[4];
      #pragma unroll
      for (int i = 0; i < 4; i++)
        af[i] = *(const short8*)(As + (wm * 64 + i * 16 + l15) * 64 + ks * 32 + quad * 8);
      #pragma unroll
      for (int j = 0; j < 4; j++)
        bf[j] = *(const short8*)(Bs + (wn * 64 + j * 16 + l15) * 64 + ks * 32 + quad * 8);
      #pragma unroll
      for (int i = 0; i < 4; i++)
        #pragma unroll
        for (int j = 0; j < 4; j++)
          acc[i][j] = __builtin_amdgcn_mfma_f32_16x16x32_bf16(af[i], bf[j], acc[i][j], 0, 0, 0);
    }
  }
  #pragma unroll
  for (int j = 0; j < 4; j++) {
    int n = n0 + wn * 64 + j * 16 + l15;
    float bval = bias[n];
    #pragma unroll
    for (int i = 0; i < 4; i++) {
      #pragma unroll
      for (int reg = 0; reg < 4; reg++) {
        int m = m0 + wm * 64 + i * 16 + quad * 4 + reg;
        out[(size_t)m * H_ + n] = acc[i][j][reg] + bval + resid[(size_t)m * H_ + n];
      }
    }
  }
}

// ------------------------------------------------------- causal flash attn
// Block = 64 q-rows x 2 paired q-tiles (qt, 31-qt) -> uniform 33 k-tiles of
// work per block. K/Vt staged cooperatively in LDS (padded, conflict-free),
// single-reg-set software pipeline: barrier; ds_write(regs); barrier; issue
// global loads for kt+1; compute kt (prefetch drains at next barrier).
// S^T formulation: lane owns one q-row (q = qr + l15); softmax = 2 shfls;
// P^T via wave-private LDS (in-order DS pipe, no barrier).
__global__ __launch_bounds__(256) void attn_kernel(
    const unsigned short* __restrict__ qw, const unsigned short* __restrict__ kw,
    const unsigned short* __restrict__ vtw, unsigned short* __restrict__ ow) {
  __shared__ unsigned short Klds[64 * 136];   // [key 64][d 128 + pad]
  __shared__ unsigned short Vtl[128 * 72];    // [d 128][key 64 + pad]
  __shared__ unsigned short Pl[4][16 * 72];   // [wave][q 16][key 64 + pad]
  int pr = blockIdx.x, bh = blockIdx.y;
  int t = threadIdx.x, lane = t & 63, wv = t >> 6;
  int l15 = lane & 15, quad = lane >> 4;
  int h = bh & 15, bb = bh >> 4;

  const float scale = 0.08838834764831845f;
  int krr = t >> 4, kcc = (t & 15) * 8;       // K staging: 16 lanes/row
  int vdd = t >> 3, vss = (t & 7) * 8;        // Vt staging: 8 lanes/row
  unsigned short* plw = &Pl[wv][0];
  const unsigned short* kgb = kw + ((size_t)bh * S_ + krr) * HD_ + kcc;
  const unsigned short* vgb = vtw + ((size_t)bh * HD_ + vdd) * S_ + vss;

  short8 kreg[4], vreg[4];
  auto load_stage = [&](int kb) {
    #pragma unroll
    for (int c = 0; c < 4; c++) {
      kreg[c] = *(const short8*)(kgb + (size_t)(kb + c * 16) * HD_);
      vreg[c] = *(const short8*)(vgb + (size_t)(c * 32) * S_ + kb);
    }
  };

  #pragma unroll 1
  for (int half = 0; half < 2; half++) {
    int qt = half ? (NQT_ - 1 - pr) : pr;
    int qr = qt * 64 + wv * 16;
    int q = qr + l15;                         // this lane's q-row

    // Q-frags (B operand): lane n=l15 -> row q; k = ks*32 + quad*8 + j
    short8 qf[4];
    {
      const unsigned short* qbase = qw + ((size_t)bh * S_ + q) * HD_ + quad * 8;
      #pragma unroll
      for (int ks = 0; ks < 4; ks++)
        qf[ks] = *(const short8*)(qbase + ks * 32);
    }

    float m_i = -INFINITY, l_i = 0.f;
    floatx4 o[8];
    #pragma unroll
    for (int ht = 0; ht < 8; ht++) o[ht] = (floatx4){0.f, 0.f, 0.f, 0.f};

    load_stage(0);                            // prime the pipeline
    #pragma unroll 1
    for (int kt = 0; kt <= qt; kt++) {
      int kb = kt * 64;
      __syncthreads();                        // prev tile's LDS reads done
      #pragma unroll
      for (int c = 0; c < 4; c++) {
        *(short8*)(Klds + (c * 16 + krr) * 136 + kcc) = kreg[c];
        *(short8*)(Vtl + (c * 32 + vdd) * 72 + vss) = vreg[c];
      }
      __syncthreads();                        // tile visible to all waves
      if (kt < qt) load_stage(kb + 64);       // prefetch overlaps compute

      // ---- S^T = K.Q^T  (A = K-frag from LDS)
      floatx4 sv[4];
      #pragma unroll
      for (int jm = 0; jm < 4; jm++) {
        sv[jm] = (floatx4){0.f, 0.f, 0.f, 0.f};
        #pragma unroll
        for (int ks = 0; ks < 4; ks++) {
          short8 kf = *(const short8*)(Klds + (jm * 16 + l15) * 136 + ks * 32 + quad * 8);
          sv[jm] = __builtin_amdgcn_mfma_f32_16x16x32_bf16(kf, qf[ks], sv[jm], 0, 0, 0);
        }
      }

      // ---- online softmax (lane holds 16 scores for its q-row)
      float p[4][4];
      float mx = m_i;
      #pragma unroll
      for (int jm = 0; jm < 4; jm++)
        #pragma unroll
        for (int reg = 0; reg < 4; reg++) {
          float v = sv[jm][reg] * scale;
          int key = kb + jm * 16 + quad * 4 + reg;
          if (key > q) v = -1e30f;
          p[jm][reg] = v;
          mx = fmaxf(mx, v);
        }
      mx = fmaxf(mx, __shfl_xor(mx, 16));
      mx = fmaxf(mx, __shfl_xor(mx, 32));
      float sum = 0.f;
      #pragma unroll
      for (int jm = 0; jm < 4; jm++)
        #pragma unroll
        for (int reg = 0; reg < 4; reg++) { p[jm][reg] = __expf(p[jm][reg] - mx); sum += p[jm][reg]; }
      sum += __shfl_xor(sum, 16);
      sum += __shfl_xor(sum, 32);
      float alpha = __expf(m_i - mx);
      l_i = l_i * alpha + sum;
      m_i = mx;
      #pragma unroll
      for (int ht = 0; ht < 8; ht++) o[ht] *= alpha;

      // ---- P^T -> wave-private LDS [q=l15][key], 8B packed
      #pragma unroll
      for (int jm = 0; jm < 4; jm++) {
        ushort4 pk;
        pk.x = f2bf(p[jm][0]); pk.y = f2bf(p[jm][1]);
        pk.z = f2bf(p[jm][2]); pk.w = f2bf(p[jm][3]);
        *(ushort4*)(plw + l15 * 72 + jm * 16 + quad * 4) = pk;
      }

      // ---- O^T += V^T.P^T  (A = Vt-frag from LDS)
      #pragma unroll
      for (int ks2 = 0; ks2 < 2; ks2++) {
        short8 pf = *(const short8*)(plw + l15 * 72 + ks2 * 32 + quad * 8);
        #pragma unroll
        for (int ht = 0; ht < 8; ht++) {
          short8 vf = *(const short8*)(Vtl + (ht * 16 + l15) * 72 + ks2 * 32 + quad * 8);
          o[ht] = __builtin_amdgcn_mfma_f32_16x16x32_bf16(vf, pf, o[ht], 0, 0, 0);
        }
      }
    }

    // ---- epilogue: lane holds O^T: q = l15-row, d = ht*16 + quad*4 + reg
    float inv = 1.0f / l_i;
    size_t base = ((size_t)(bb * S_ + q)) * H_ + h * HD_ + quad * 4;
    #pragma unroll
    for (int ht = 0; ht < 8; ht++) {
      ushort4 ov;
      ov.x = f2bf(o[ht][0] * inv); ov.y = f2bf(o[ht][1] * inv);
      ov.z = f2bf(o[ht][2] * inv); ov.w = f2bf(o[ht][3] * inv);
      *(ushort4*)(ow + base + ht * 16) = ov;
    }
  }
}

// ---------------------------------------------------------------- launcher
extern "C" void kernel_launch(void* const* d_in, const int* in_sizes, int n_in,
                              void* d_out, int out_size, void* d_ws, size_t ws_size,
                              hipStream_t stream) {
  (void)in_sizes; (void)n_in; (void)out_size; (void)ws_size;
  const float* x      = (const float*)d_in[0];
  const float* ln_w   = (const float*)d_in[1];
  const float* ln_b   = (const float*)d_in[2];
  const float* attn_w = (const float*)d_in[3];
  const float* attn_b = (const float*)d_in[4];
  const float* proj_w = (const float*)d_in[5];
  const float* proj_b = (const float*)d_in[6];
  float* out = (float*)d_out;

  char* ws = (char*)d_ws;
  size_t off = 0;
  auto alloc = [&](size_t bytes) {
    char* p = ws + off;
    off += (bytes + 255) & ~(size_t)255;
    return p;
  };
  unsigned short* xn     = (unsigned short*)alloc((size_t)M_ * H_ * 2);
  unsigned short* wqkvt  = (unsigned short*)alloc((size_t)N3_ * H_ * 2);
  unsigned short* wprojt = (unsigned short*)alloc((size_t)H_ * H_ * 2);
  unsigned short* qws    = (unsigned short*)alloc((size_t)M_ * H_ * 2);
  unsigned short* kws    = (unsigned short*)alloc((size_t)M_ * H_ * 2);
  unsigned short* vtws   = (unsigned short*)alloc((size_t)M_ * H_ * 2);
  unsigned short* attn_out = xn;   // xn dead after qkv_gemm — alias

  ln_kernel<<<M_, 256, 0, stream>>>(x, ln_w, ln_b, xn);
  transpose_f2b<<<dim3(N3_ / 32, H_ / 32), 256, 0, stream>>>(attn_w, wqkvt, H_, N3_);
  transpose_f2b<<<dim3(H_ / 32, H_ / 32), 256, 0, stream>>>(proj_w, wprojt, H_, H_);
  qkv_gemm<<<dim3(N3_ / 128, M_ / 128), 256, 0, stream>>>(xn, wqkvt, attn_b, qws, kws, vtws);
  attn_kernel<<<dim3(NQT_ / 2, B_ * NH_), 256, 0, stream>>>(qws, kws, vtws, attn_out);
  proj_gemm<<<dim3(H_ / 128, M_ / 128), 256, 0, stream>>>(attn_out, wprojt, proj_b, x, out);
}